// Round 13
// baseline (6165.076 us; speedup 1.0000x reference)
//
#include <hip/hip_runtime.h>
#include <hip/hip_bf16.h>
#include <math.h>

#define DEV __device__ __forceinline__

typedef __attribute__((ext_vector_type(4))) float f32x4;
typedef __attribute__((ext_vector_type(8))) short bf16x8;
typedef __attribute__((ext_vector_type(4))) short s16x4;

static constexpr int Bz = 32, Lz = 400, Cz = 1024, MLPz = 4096;
static constexpr int BL = Bz * Lz;  // 12800

DEV float bf2f(unsigned short u) {
  union { unsigned int i; float f; } v; v.i = ((unsigned int)u) << 16; return v.f;
}
DEV unsigned short f2bf(float f) {
  union { float f; unsigned int i; } v; v.f = f;
  unsigned int r = v.i + 0x7FFFu + ((v.i >> 16) & 1u);
  return (unsigned short)(r >> 16);
}

DEV int level_of(int l) {
  const int cum[13] = {1,3,6,10,16,25,38,57,84,124,184,272,400};
  int lv = 12;
  #pragma unroll
  for (int i = 12; i >= 0; i--) if (l < cum[i]) lv = i;
  return lv;
}
DEV int row_kmax(int l) {
  const int cum[13] = {1,3,6,10,16,25,38,57,84,124,184,272,400};
  int km = 400;
  #pragma unroll
  for (int i = 12; i >= 0; i--) if (l < cum[i]) km = cum[i];
  return km;
}

DEV void stage16(const unsigned short* g, unsigned short* l) {
#if __has_builtin(__builtin_amdgcn_global_load_lds)
  __builtin_amdgcn_global_load_lds((const __attribute__((address_space(1))) void*)g,
                                   (__attribute__((address_space(3))) void*)l, 16, 0, 0);
#else
  *(bf16x8*)l = *(const bf16x8*)g;
#endif
}

// ------------------------------------------------------- weight transpose/convert
__global__ __launch_bounds__(256)
void tconv_k(const float* __restrict__ in, unsigned short* __restrict__ out, int K, int N)
{
  __shared__ float t[64][65];
  const int n0 = blockIdx.x * 64, k0 = blockIdx.y * 64;
  #pragma unroll
  for (int i = 0; i < 16; i++) {
    int idx = i * 256 + threadIdx.x;
    int r = idx >> 6, c = idx & 63;
    t[r][c] = in[(size_t)(k0 + r) * N + n0 + c];
  }
  __syncthreads();
  #pragma unroll
  for (int i = 0; i < 16; i++) {
    int idx = i * 256 + threadIdx.x;
    int rn = idx >> 6, ck = idx & 63;
    out[(size_t)(n0 + rn) * K + k0 + ck] = f2bf(t[ck][rn]);
  }
}

// exact-grid merged per-depth transpose (q, kv, proj, fc1; all K=1024).
__global__ __launch_bounds__(256)
void tconv5_k(const float* __restrict__ qw, const float* __restrict__ kvw,
              const float* __restrict__ pjw, const float* __restrict__ f1w,
              unsigned short* __restrict__ qwt, unsigned short* __restrict__ kvwt,
              unsigned short* __restrict__ pjwt, unsigned short* __restrict__ f1wt)
{
  const int bid = blockIdx.x;
  const float* in; unsigned short* out; int N, n0, k0;
  if (bid < 256)       { in = qw;  out = qwt;  N = 1024; int t = bid;        n0 = (t & 15) * 64; k0 = (t >> 4) * 64; }
  else if (bid < 768)  { in = kvw; out = kvwt; N = 2048; int t = bid - 256;  n0 = (t & 31) * 64; k0 = (t >> 5) * 64; }
  else if (bid < 1024) { in = pjw; out = pjwt; N = 1024; int t = bid - 768;  n0 = (t & 15) * 64; k0 = (t >> 4) * 64; }
  else                 { in = f1w; out = f1wt; N = 4096; int t = bid - 1024; n0 = (t & 63) * 64; k0 = (t >> 6) * 64; }
  __shared__ float tt[64][65];
  #pragma unroll
  for (int i = 0; i < 16; i++) {
    int idx = i * 256 + threadIdx.x;
    int r = idx >> 6, c = idx & 63;
    tt[r][c] = in[(size_t)(k0 + r) * N + n0 + c];
  }
  __syncthreads();
  #pragma unroll
  for (int i = 0; i < 16; i++) {
    int idx = i * 256 + threadIdx.x;
    int rn = idx >> 6, ck = idx & 63;
    out[(size_t)(n0 + rn) * 1024 + k0 + ck] = f2bf(tt[ck][rn]);
  }
}

// ---------------------------------------------------------------- GEMM (m97-style, proven round-3 form)
// RULE (r5): with the 128x128/4-wave kernel, (256,2) is proven; do not tighten.
enum { EP_BF16 = 0, EP_GELU = 1, EP_RESID = 2, EP_F32 = 3, EP_KV = 4 };

template<int MODE>
__global__ __launch_bounds__(256, 2)
void gemm2_k(const unsigned short* __restrict__ A, const unsigned short* __restrict__ Bt,
             const float* __restrict__ bias, void* __restrict__ out,
             float* __restrict__ xres, const float* __restrict__ gsh,
             const float* __restrict__ gpb, unsigned short* __restrict__ vtb,
             int N, int K)
{
  __shared__ unsigned short As[128 * 64];
  __shared__ unsigned short Bs[128 * 64];
  const int tid = threadIdx.x;
  const int lane = tid & 63, wv = tid >> 6;
  const int row0 = blockIdx.x * 128, col0 = blockIdx.y * 128;
  const int wm = (wv >> 1) * 64, wn = (wv & 1) * 64;

  f32x4 acc[4][4] = {};

  for (int k0 = 0; k0 < K; k0 += 64) {
    #pragma unroll
    for (int i = 0; i < 4; i++) {
      int ch = i * 256 + tid;
      int r = ch >> 3;
      int c8 = (ch & 7) ^ (r & 7);
      stage16(A + (size_t)(row0 + r) * K + k0 + c8 * 8, As + ch * 8);
    }
    #pragma unroll
    for (int i = 0; i < 4; i++) {
      int ch = i * 256 + tid;
      int r = ch >> 3;
      int c8 = (ch & 7) ^ (r & 7);
      stage16(Bt + (size_t)(col0 + r) * K + k0 + c8 * 8, Bs + ch * 8);
    }
    __syncthreads();
    #pragma unroll
    for (int kk = 0; kk < 2; kk++) {
      bf16x8 af[4], bfr[4];
      const int bcol = kk * 64 + (lane >> 4) * 16;
      #pragma unroll
      for (int m = 0; m < 4; m++) {
        int r = wm + m * 16 + (lane & 15);
        af[m] = *(const bf16x8*)((char*)As + r * 128 + (bcol ^ ((r & 7) << 4)));
      }
      #pragma unroll
      for (int n = 0; n < 4; n++) {
        int r = wn + n * 16 + (lane & 15);
        bfr[n] = *(const bf16x8*)((char*)Bs + r * 128 + (bcol ^ ((r & 7) << 4)));
      }
      #pragma unroll
      for (int m = 0; m < 4; m++)
        #pragma unroll
        for (int n = 0; n < 4; n++)
          acc[m][n] = __builtin_amdgcn_mfma_f32_16x16x32_bf16(af[m], bfr[n], acc[m][n], 0, 0, 0);
    }
    __syncthreads();
  }

  const int rbase = row0 + wm + ((lane >> 4) << 2);
  const int cbase = col0 + wn + (lane & 15);
  #pragma unroll
  for (int n = 0; n < 4; n++) {
    int gcol = cbase + n * 16;
    float bv = bias[gcol];
    #pragma unroll
    for (int m = 0; m < 4; m++) {
      #pragma unroll
      for (int r = 0; r < 4; r++) {
        int grow = rbase + m * 16 + r;
        float v = acc[m][n][r] + bv;
        if constexpr (MODE == EP_BF16) {
          ((unsigned short*)out)[(size_t)grow * N + gcol] = f2bf(v);
        } else if constexpr (MODE == EP_GELU) {
          float g = 0.5f * v * (1.f + erff(v * 0.70710678118654752f));
          ((unsigned short*)out)[(size_t)grow * N + gcol] = f2bf(g);
        } else if constexpr (MODE == EP_RESID) {
          int b = grow / Lz;
          float g = gsh[gcol] + gpb[(size_t)b * 6144 + gcol];
          xres[(size_t)grow * Cz + gcol] += g * v;
        } else if constexpr (MODE == EP_KV) {
          if (gcol < 1024) {
            ((unsigned short*)out)[(size_t)grow * 1024 + gcol] = f2bf(v);  // K row-major
          } else {
            int b = grow / Lz, l = grow - b * Lz;
            int h = (gcol >> 6) & 15, d = gcol & 63;
            vtb[(((size_t)b * 16 + h) * 64 + d) * Lz + l] = f2bf(v);      // V transposed
          }
        } else {
          ((float*)out)[(size_t)grow * N + gcol] = v;
        }
      }
    }
  }
}

// ---------------------------------------------------------------- GEMM v4: 256(M) x 128(N), 8 waves
// r5 retry with the register-cap theory fix: __launch_bounds__(512, 2) gives a
// 256-reg cap (kernel needs ~124) instead of r5's fatal 128-cap at (512,4).
// Natural block mapping (swizzle measured harmful r6). 48KB LDS -> 2 blocks/CU.
template<int MODE>
__global__ __launch_bounds__(512, 2)
void gemm4_k(const unsigned short* __restrict__ A, const unsigned short* __restrict__ Bt,
             const float* __restrict__ bias, void* __restrict__ out,
             float* __restrict__ xres, const float* __restrict__ gsh,
             const float* __restrict__ gpb, int N, int K)
{
  __shared__ unsigned short As[256 * 64];   // 32 KB
  __shared__ unsigned short Bs[128 * 64];   // 16 KB
  const int tid = threadIdx.x;
  const int lane = tid & 63, wid = tid >> 6;
  const int wm = wid >> 1;   // 0..3 (M quadrant)
  const int wn = wid & 1;    // 0..1 (N half)
  const int row0 = blockIdx.x * 256, col0 = blockIdx.y * 128;

  f32x4 acc[4][4] = {};

  for (int k0 = 0; k0 < K; k0 += 64) {
    #pragma unroll
    for (int i = 0; i < 4; i++) {
      int ch = i * 512 + tid;
      int r = ch >> 3, c8 = (ch & 7) ^ (r & 7);
      stage16(A + (size_t)(row0 + r) * K + k0 + c8 * 8, As + ch * 8);
    }
    #pragma unroll
    for (int i = 0; i < 2; i++) {
      int ch = i * 512 + tid;
      int r = ch >> 3, c8 = (ch & 7) ^ (r & 7);
      stage16(Bt + (size_t)(col0 + r) * K + k0 + c8 * 8, Bs + ch * 8);
    }
    __syncthreads();
    #pragma unroll
    for (int kk = 0; kk < 2; kk++) {
      bf16x8 af[4], bfr[4];
      const int bcol = kk * 64 + (lane >> 4) * 16;
      #pragma unroll
      for (int m = 0; m < 4; m++) {
        int r = wm * 64 + m * 16 + (lane & 15);
        af[m] = *(const bf16x8*)((char*)As + r * 128 + (bcol ^ ((r & 7) << 4)));
      }
      #pragma unroll
      for (int n = 0; n < 4; n++) {
        int r = wn * 64 + n * 16 + (lane & 15);
        bfr[n] = *(const bf16x8*)((char*)Bs + r * 128 + (bcol ^ ((r & 7) << 4)));
      }
      #pragma unroll
      for (int m = 0; m < 4; m++)
        #pragma unroll
        for (int n = 0; n < 4; n++)
          acc[m][n] = __builtin_amdgcn_mfma_f32_16x16x32_bf16(af[m], bfr[n], acc[m][n], 0, 0, 0);
    }
    __syncthreads();
  }

  const int rbase = row0 + wm * 64 + ((lane >> 4) << 2);
  const int cbase = col0 + wn * 64 + (lane & 15);
  #pragma unroll
  for (int n = 0; n < 4; n++) {
    int gcol = cbase + n * 16;
    float bv = bias[gcol];
    #pragma unroll
    for (int m = 0; m < 4; m++) {
      #pragma unroll
      for (int r = 0; r < 4; r++) {
        int grow = rbase + m * 16 + r;
        float v = acc[m][n][r] + bv;
        if constexpr (MODE == EP_GELU) {
          float g = 0.5f * v * (1.f + erff(v * 0.70710678118654752f));
          ((unsigned short*)out)[(size_t)grow * N + gcol] = f2bf(g);
        } else if constexpr (MODE == EP_RESID) {
          int b = grow / Lz;
          float g = gsh[gcol] + gpb[(size_t)b * 6144 + gcol];
          xres[(size_t)grow * Cz + gcol] += g * v;
        } else {
          ((float*)out)[(size_t)grow * N + gcol] = v;
        }
      }
    }
  }
}

// ---------------------------------------------------------------- merged q + kv GEMM (K=1024)
__global__ __launch_bounds__(256, 2)
void qkv_k(const unsigned short* __restrict__ xn, const unsigned short* __restrict__ poc,
           const unsigned short* __restrict__ qwt, const unsigned short* __restrict__ kvwt,
           const float* __restrict__ q_bias, const float* __restrict__ kv_bias,
           unsigned short* __restrict__ qbf, unsigned short* __restrict__ kbuf,
           unsigned short* __restrict__ vtb)
{
  __shared__ unsigned short As[128 * 64];
  __shared__ unsigned short Bs[128 * 64];
  const int tid = threadIdx.x;
  const int lane = tid & 63, wv = tid >> 6;
  const bool isq = blockIdx.y < 8;
  const unsigned short* A  = isq ? xn : poc;
  const unsigned short* Bt = isq ? qwt : kvwt;
  const float* bias        = isq ? q_bias : kv_bias;
  const int K = 1024;
  const int row0 = blockIdx.x * 128;
  const int col0 = (isq ? blockIdx.y : (blockIdx.y - 8)) * 128;
  const int wm = (wv >> 1) * 64, wn = (wv & 1) * 64;

  f32x4 acc[4][4] = {};

  for (int k0 = 0; k0 < K; k0 += 64) {
    #pragma unroll
    for (int i = 0; i < 4; i++) {
      int ch = i * 256 + tid;
      int r = ch >> 3;
      int c8 = (ch & 7) ^ (r & 7);
      stage16(A + (size_t)(row0 + r) * K + k0 + c8 * 8, As + ch * 8);
    }
    #pragma unroll
    for (int i = 0; i < 4; i++) {
      int ch = i * 256 + tid;
      int r = ch >> 3;
      int c8 = (ch & 7) ^ (r & 7);
      stage16(Bt + (size_t)(col0 + r) * K + k0 + c8 * 8, Bs + ch * 8);
    }
    __syncthreads();
    #pragma unroll
    for (int kk = 0; kk < 2; kk++) {
      bf16x8 af[4], bfr[4];
      const int bcol = kk * 64 + (lane >> 4) * 16;
      #pragma unroll
      for (int m = 0; m < 4; m++) {
        int r = wm + m * 16 + (lane & 15);
        af[m] = *(const bf16x8*)((char*)As + r * 128 + (bcol ^ ((r & 7) << 4)));
      }
      #pragma unroll
      for (int n = 0; n < 4; n++) {
        int r = wn + n * 16 + (lane & 15);
        bfr[n] = *(const bf16x8*)((char*)Bs + r * 128 + (bcol ^ ((r & 7) << 4)));
      }
      #pragma unroll
      for (int m = 0; m < 4; m++)
        #pragma unroll
        for (int n = 0; n < 4; n++)
          acc[m][n] = __builtin_amdgcn_mfma_f32_16x16x32_bf16(af[m], bfr[n], acc[m][n], 0, 0, 0);
    }
    __syncthreads();
  }

  const int rbase = row0 + wm + ((lane >> 4) << 2);
  const int cbase = col0 + wn + (lane & 15);
  #pragma unroll
  for (int n = 0; n < 4; n++) {
    int gcol = cbase + n * 16;
    float bv = bias[gcol];
    #pragma unroll
    for (int m = 0; m < 4; m++) {
      #pragma unroll
      for (int r = 0; r < 4; r++) {
        int grow = rbase + m * 16 + r;
        float v = acc[m][n][r] + bv;
        if (isq) {
          qbf[(size_t)grow * 1024 + gcol] = f2bf(v);
        } else if (gcol < 1024) {
          kbuf[(size_t)grow * 1024 + gcol] = f2bf(v);
        } else {
          int b = grow / Lz, l = grow - b * Lz;
          int h = (gcol >> 6) & 15, d = gcol & 63;
          vtb[(((size_t)b * 16 + h) * 64 + d) * Lz + l] = f2bf(v);
        }
      }
    }
  }
}

// ---------------------------------------------------------------- embed prep: f32 -> bf16 A matrices
__global__ __launch_bounds__(256)
void eprep_k(const float* __restrict__ src0, const float* __restrict__ src1,
             unsigned short* __restrict__ A0, unsigned short* __restrict__ A1)
{
  const int chunk = blockIdx.x * 256 + threadIdx.x;
  const int row = chunk >> 3, k8 = (chunk & 7) * 8;
  bf16x8 o;
  if (blockIdx.y == 0) {
    const int b = row / Lz, l = row - b * Lz;
    if (l == 0) {
      #pragma unroll
      for (int i = 0; i < 8; i++) o[i] = 0;
    } else {
      const float* s = src0 + ((size_t)b * (Lz - 1) + (l - 1)) * 64 + k8;
      #pragma unroll
      for (int i = 0; i < 8; i++) o[i] = (short)f2bf(s[i]);
    }
    *(bf16x8*)(A0 + (size_t)row * 64 + k8) = o;
  } else {
    const float* s = src1 + (size_t)row * 64 + k8;
    #pragma unroll
    for (int i = 0; i < 8; i++) o[i] = (short)f2bf(s[i]);
    *(bf16x8*)(A1 + (size_t)row * 64 + k8) = o;
  }
}

// ---------------------------------------------------------------- embed GEMM: K=64, single K-step
__global__ __launch_bounds__(256, 2)
void egemm_k(const unsigned short* __restrict__ A0, const unsigned short* __restrict__ A1,
             const unsigned short* __restrict__ wwt, const float* __restrict__ wb,
             const float* __restrict__ ltab, const float* __restrict__ pos1,
             const float* __restrict__ cond, const float* __restrict__ pos_start,
             float* __restrict__ xout, unsigned short* __restrict__ pocout)
{
  __shared__ unsigned short As[128 * 64];
  __shared__ unsigned short Bs[128 * 64];
  const int tid = threadIdx.x;
  const int lane = tid & 63, wv = tid >> 6;
  const int mode = blockIdx.y >> 3;
  const int col0 = (blockIdx.y & 7) * 128;
  const int row0 = blockIdx.x * 128;
  const unsigned short* A = mode ? A1 : A0;
  const int wm = (wv >> 1) * 64, wn = (wv & 1) * 64;

  f32x4 acc[4][4] = {};

  #pragma unroll
  for (int i = 0; i < 4; i++) {
    int ch = i * 256 + tid;
    int r = ch >> 3;
    int c8 = (ch & 7) ^ (r & 7);
    stage16(A + (size_t)(row0 + r) * 64 + c8 * 8, As + ch * 8);
  }
  #pragma unroll
  for (int i = 0; i < 4; i++) {
    int ch = i * 256 + tid;
    int r = ch >> 3;
    int c8 = (ch & 7) ^ (r & 7);
    stage16(wwt + (size_t)(col0 + r) * 64 + c8 * 8, Bs + ch * 8);
  }
  __syncthreads();
  #pragma unroll
  for (int kk = 0; kk < 2; kk++) {
    bf16x8 af[4], bfr[4];
    const int bcol = kk * 64 + (lane >> 4) * 16;
    #pragma unroll
    for (int m = 0; m < 4; m++) {
      int r = wm + m * 16 + (lane & 15);
      af[m] = *(const bf16x8*)((char*)As + r * 128 + (bcol ^ ((r & 7) << 4)));
    }
    #pragma unroll
    for (int n = 0; n < 4; n++) {
      int r = wn + n * 16 + (lane & 15);
      bfr[n] = *(const bf16x8*)((char*)Bs + r * 128 + (bcol ^ ((r & 7) << 4)));
    }
    #pragma unroll
    for (int m = 0; m < 4; m++)
      #pragma unroll
      for (int n = 0; n < 4; n++)
        acc[m][n] = __builtin_amdgcn_mfma_f32_16x16x32_bf16(af[m], bfr[n], acc[m][n], 0, 0, 0);
  }

  const int rbase = row0 + wm + ((lane >> 4) << 2);
  const int cbase = col0 + wn + (lane & 15);
  #pragma unroll
  for (int n = 0; n < 4; n++) {
    int gcol = cbase + n * 16;
    float bv = wb[gcol];
    #pragma unroll
    for (int m = 0; m < 4; m++) {
      #pragma unroll
      for (int r = 0; r < 4; r++) {
        int grow = rbase + m * 16 + r;
        int b = grow / Lz, l = grow - b * Lz;
        float base = ltab[(size_t)level_of(l) * Cz + gcol] + pos1[(size_t)l * Cz + gcol];
        float v = acc[m][n][r] + bv + base;
        if (mode == 0) {
          if (l == 0) v = cond[(size_t)b * Cz + gcol] + pos_start[gcol] + ltab[gcol] + pos1[gcol];
          xout[(size_t)grow * Cz + gcol] = v;
        } else {
          pocout[(size_t)grow * Cz + gcol] = f2bf(v);
        }
      }
    }
  }
}

// ---------------------------------------------------------------- LayerNorm v2: wave-per-row, no barriers
__global__ __launch_bounds__(256)
void ln2_k(const float* __restrict__ x, unsigned short* __restrict__ out,
           const float* __restrict__ ssh, const float* __restrict__ spb, int sstride,
           const float* __restrict__ hsh, const float* __restrict__ hpb, int hstride)
{
  const int wv = threadIdx.x >> 6, lane = threadIdx.x & 63;
  const int row = blockIdx.x * 4 + wv;
  const int b = row / Lz;
  const float* xr = x + (size_t)row * Cz;
  f32x4 v[4];
  float s1 = 0.f;
  #pragma unroll
  for (int j = 0; j < 4; j++) {
    v[j] = *(const f32x4*)(xr + j * 256 + lane * 4);
    s1 += v[j][0] + v[j][1] + v[j][2] + v[j][3];
  }
  #pragma unroll
  for (int o = 32; o > 0; o >>= 1) s1 += __shfl_xor(s1, o, 64);
  float mean = s1 * (1.f / 1024.f);
  float s2 = 0.f;
  #pragma unroll
  for (int j = 0; j < 4; j++)
    #pragma unroll
    for (int i = 0; i < 4; i++) { float d = v[j][i] - mean; s2 += d * d; }
  #pragma unroll
  for (int o = 32; o > 0; o >>= 1) s2 += __shfl_xor(s2, o, 64);
  float rstd = rsqrtf(s2 * (1.f / 1024.f) + 1e-6f);
  #pragma unroll
  for (int j = 0; j < 4; j++) {
    s16x4 o4;
    #pragma unroll
    for (int i = 0; i < 4; i++) {
      int c = j * 256 + lane * 4 + i;
      float sc = (ssh ? ssh[c] : 0.f) + spb[(size_t)b * sstride + c];
      float sh = (hsh ? hsh[c] : 0.f) + hpb[(size_t)b * hstride + c];
      o4[i] = (short)f2bf((v[j][i] - mean) * rstd * (1.f + sc) + sh);
    }
    *(s16x4*)(&out[(size_t)row * Cz + j * 256 + lane * 4]) = o4;
  }
}

// ---------------------------------------------------------------- attention v6 (MFMA PV)
__global__ __launch_bounds__(512)
void attn3_k(const unsigned short* __restrict__ qb,
             const unsigned short* __restrict__ kbuf,
             const unsigned short* __restrict__ vtb,
             unsigned short* __restrict__ ob)
{
  __shared__ unsigned short Ks[400 * 64];     // swizzled rows, 128 B/row
  __shared__ unsigned short Vt[64 * 408];     // V^T, pitch 816 B
  __shared__ unsigned short Pl[8][512];       // per-wave P buffer (16q x 32k bf16)
  const int bh = blockIdx.x, b = bh >> 4, h = bh & 15;
  const int qc = blockIdx.y;
  const int tid = threadIdx.x;
  const int q0 = qc * 128;
  const int nch = (row_kmax(min(q0 + 127, Lz - 1)) + 15) >> 4;

  const size_t kbase = (size_t)b * Lz * 1024 + h * 64;
  for (int i = tid; i < nch * 128; i += 512) {
    int l = i >> 3, d8 = i & 7;
    bf16x8 kr = *(const bf16x8*)&kbuf[kbase + (size_t)l * 1024 + d8 * 8];
    *(bf16x8*)((char*)Ks + l * 128 + ((d8 * 16) ^ ((l & 7) << 4))) = kr;
  }
  const size_t vbase = ((size_t)b * 16 + h) * 64 * Lz;
  const int vch = nch * 2;                     // staged 16B chunks per d-row
  for (int i = tid; i < 3200; i += 512) {      // 64 d-rows x 50 chunk slots
    int d = i / 50, c8 = i - d * 50;           // constant divisor -> magic mul
    if (c8 < vch)
      *(bf16x8*)((char*)Vt + d * 816 + c8 * 16) = *(const bf16x8*)&vtb[vbase + (size_t)d * Lz + c8 * 8];
  }
  __syncthreads();

  const int wv = tid >> 6, lane = tid & 63, g = lane >> 4, q = lane & 15;
  const int qw0 = q0 + wv * 16;
  if (qw0 >= Lz) return;
  const int qrow = qw0 + q;
  const int my_kmax = row_kmax(qrow);
  const int nsch = (row_kmax(qw0 + 15) + 31) >> 5;
  const int vclamp = nch * 16 - 8;             // max legal 8-elem fragment start

  const unsigned short* qp = qb + (size_t)(b * Lz + qrow) * Cz + h * 64;
  bf16x8 qf0 = *(const bf16x8*)(qp + g * 8);
  bf16x8 qf1 = *(const bf16x8*)(qp + 32 + g * 8);
  unsigned short* myP = &Pl[wv][0];

  float m = -30000.f, lsum = 0.f;
  f32x4 acc[4] = {};

  for (int sc = 0; sc < nsch; ++sc) {
    f32x4 st0 = {0.f,0.f,0.f,0.f}, st1 = {0.f,0.f,0.f,0.f};
    {
      int kr = sc * 32 + q;
      const char* kb = (const char*)Ks + kr * 128;
      int sw = (kr & 7) << 4;
      bf16x8 k0 = *(const bf16x8*)(kb + ((g * 16) ^ sw));
      bf16x8 k1 = *(const bf16x8*)(kb + ((64 + g * 16) ^ sw));
      st0 = __builtin_amdgcn_mfma_f32_16x16x32_bf16(k0, qf0, st0, 0, 0, 0);
      st0 = __builtin_amdgcn_mfma_f32_16x16x32_bf16(k1, qf1, st0, 0, 0, 0);
    }
    {
      int kr = sc * 32 + 16 + q;
      const char* kb = (const char*)Ks + kr * 128;
      int sw = (kr & 7) << 4;
      bf16x8 k0 = *(const bf16x8*)(kb + ((g * 16) ^ sw));
      bf16x8 k1 = *(const bf16x8*)(kb + ((64 + g * 16) ^ sw));
      st1 = __builtin_amdgcn_mfma_f32_16x16x32_bf16(k0, qf0, st1, 0, 0, 0);
      st1 = __builtin_amdgcn_mfma_f32_16x16x32_bf16(k1, qf1, st1, 0, 0, 0);
    }

    float s8[8]; float cmax = -30000.f;
    #pragma unroll
    for (int r = 0; r < 4; r++) {
      int k0g = sc * 32 + 4 * g + r;
      int k1g = k0g + 16;
      s8[r]     = (k0g < my_kmax) ? st0[r] * 0.125f : -30000.f;
      s8[4 + r] = (k1g < my_kmax) ? st1[r] * 0.125f : -30000.f;
      cmax = fmaxf(cmax, fmaxf(s8[r], s8[4 + r]));
    }
    cmax = fmaxf(cmax, __shfl_xor(cmax, 16, 64));
    cmax = fmaxf(cmax, __shfl_xor(cmax, 32, 64));

    if (!__all(cmax <= m + 8.f)) {
      float mnew = fmaxf(m, cmax);
      float f = __expf(m - mnew);
      lsum *= f;
      #pragma unroll
      for (int blk = 0; blk < 4; blk++)
        #pragma unroll
        for (int j = 0; j < 4; j++) acc[blk][j] *= f;
      m = mnew;
    }

    float p[8], ps = 0.f;
    #pragma unroll
    for (int r = 0; r < 8; r++) { p[r] = __expf(s8[r] - m); ps += p[r]; }
    ps += __shfl_xor(ps, 16, 64);
    ps += __shfl_xor(ps, 32, 64);
    lsum += ps;

    #pragma unroll
    for (int cp = 0; cp < 2; cp++) {
      #pragma unroll
      for (int j = 0; j < 2; j++) {
        unsigned int pk;
        asm("v_cvt_pk_bf16_f32 %0, %1, %2" : "=v"(pk)
            : "v"(p[4 * cp + 2 * j]), "v"(p[4 * cp + 2 * j + 1]));
        int w = 8 * cp + 2 * g + j;
        *(unsigned int*)((char*)myP + q * 64 + 4 * (w ^ q)) = pk;
      }
    }

    unsigned int pw[4];
    #pragma unroll
    for (int i = 0; i < 4; i++)
      pw[i] = *(const unsigned int*)((const char*)myP + q * 64 + 4 * ((4 * g + i) ^ q));
    bf16x8 pfrag;
    #pragma unroll
    for (int i = 0; i < 4; i++) {
      pfrag[2 * i]     = (short)(pw[i] & 0xFFFF);
      pfrag[2 * i + 1] = (short)(pw[i] >> 16);
    }

    const int koff = min(sc * 32 + 8 * g, vclamp);   // clamp into staged region
    #pragma unroll
    for (int blk = 0; blk < 4; blk++) {
      bf16x8 vf = *(const bf16x8*)((const char*)Vt + (16 * blk + q) * 816 + koff * 2);
      acc[blk] = __builtin_amdgcn_mfma_f32_16x16x32_bf16(vf, pfrag, acc[blk], 0, 0, 0);
    }
  }

  float inv = 1.f / lsum;
  unsigned short* op = ob + (size_t)(b * Lz + qrow) * Cz + h * 64;
  #pragma unroll
  for (int blk = 0; blk < 4; blk++)
    #pragma unroll
    for (int r = 0; r < 4; r++)
      op[16 * blk + 4 * g + r] = f2bf(acc[blk][r] * inv);
}

// ---------------------------------------------------------------- preamble
__global__ __launch_bounds__(256)
void cond_k(const float* __restrict__ pc, const float* __restrict__ pw,
            const float* __restrict__ pb, float* __restrict__ cond,
            float* __restrict__ silu)
{
  const int b = blockIdx.y;
  const int n = blockIdx.x * 256 + threadIdx.x;
  __shared__ float a[256];
  a[threadIdx.x] = pc[b * 256 + threadIdx.x];
  __syncthreads();
  float s = pb[n];
  for (int k = 0; k < 256; k++) s += a[k] * pw[(size_t)k * Cz + n];
  cond[(size_t)b * Cz + n] = s;
  silu[(size_t)b * Cz + n] = s / (1.f + __expf(-s));
}

__global__ __launch_bounds__(256)
void smallmm_k(const float* __restrict__ A, const float* __restrict__ W,
               const float* __restrict__ bias, float* __restrict__ out, int N)
{
  const int b = blockIdx.y;
  const int n = blockIdx.x * 256 + threadIdx.x;
  __shared__ float a[1024];
  for (int i = threadIdx.x; i < 1024; i += 256) a[i] = A[(size_t)b * 1024 + i];
  __syncthreads();
  float s = bias[n];
  for (int k = 0; k < 1024; k++) s += a[k] * W[(size_t)k * N + n];
  out[(size_t)b * N + n] = s;
}

// ---------------------------------------------------------------- launch
extern "C" void kernel_launch(void* const* d_in, const int* in_sizes, int n_in,
                              void* d_out, int out_size, void* d_ws, size_t ws_size,
                              hipStream_t stream)
{
  (void)in_sizes; (void)n_in; (void)out_size; (void)ws_size;
  const float* x_blcv   = (const float*)d_in[0];
  const float* poc_ctx  = (const float*)d_in[1];
  const float* poc_cond = (const float*)d_in[2];
  const float* word_w   = (const float*)d_in[3];
  const float* word_b   = (const float*)d_in[4];
  const float* poc_w    = (const float*)d_in[5];
  const float* poc_b    = (const float*)d_in[6];
  const float* pos_start= (const float*)d_in[7];
  const float* pos_1lc  = (const float*)d_in[8];
  const float* lvl_tab  = (const float*)d_in[9];
  const float* ada_w    = (const float*)d_in[10];
  const float* ada_b    = (const float*)d_in[11];
  const float* ada_gss  = (const float*)d_in[12];
  const float* q_w      = (const float*)d_in[13];
  const float* q_b      = (const float*)d_in[14];
  const float* kv_w     = (const float*)d_in[15];
  const float* kv_b     = (const float*)d_in[16];
  const float* proj_w   = (const float*)d_in[17];
  const float* proj_b   = (const float*)d_in[18];
  const float* fc1_w    = (const float*)d_in[19];
  const float* fc1_b    = (const float*)d_in[20];
  const float* fc2_w    = (const float*)d_in[21];
  const float* fc2_b    = (const float*)d_in[22];
  const float* head_ada_w = (const float*)d_in[23];
  const float* head_ada_b = (const float*)d_in[24];
  const float* head_w   = (const float*)d_in[25];
  const float* head_b   = (const float*)d_in[26];

  char* p = (char*)d_ws;
  auto carve = [&](size_t bytes) { void* r = (void*)p; p += (bytes + 255) & ~(size_t)255; return r; };
  float* x            = (float*)carve((size_t)BL * Cz * 4);
  unsigned short* xn  = (unsigned short*)carve((size_t)BL * Cz * 2);
  unsigned short* poc = (unsigned short*)carve((size_t)BL * Cz * 2);
  unsigned short* qbf = (unsigned short*)carve((size_t)BL * Cz * 2);
  unsigned short* kbuf= (unsigned short*)carve((size_t)BL * Cz * 2);
  unsigned short* vtb = (unsigned short*)carve((size_t)BL * Cz * 2);
  unsigned short* ob  = (unsigned short*)carve((size_t)BL * Cz * 2);
  unsigned short* hdn = (unsigned short*)carve((size_t)BL * MLPz * 2);
  unsigned short* wt  = (unsigned short*)carve((size_t)12582912 * 2);
  unsigned short* A0  = (unsigned short*)carve((size_t)BL * 64 * 2);
  unsigned short* A1  = (unsigned short*)carve((size_t)BL * 64 * 2);
  unsigned short* wwt = (unsigned short*)carve((size_t)1024 * 64 * 2);
  float* cond  = (float*)carve(32 * 1024 * 4);
  float* siluc = (float*)carve(32 * 1024 * 4);
  float* gss   = (float*)carve(32 * 6144 * 4);
  float* ss    = (float*)carve(32 * 2048 * 4);

  unsigned short* qwt  = wt;
  unsigned short* kvwt = wt + 1048576;
  unsigned short* pjwt = wt + 3145728;
  unsigned short* f1wt = wt + 4194304;
  unsigned short* f2wt = wt + 8388608;

  cond_k<<<dim3(4, 32), 256, 0, stream>>>(poc_cond, poc_w, poc_b, cond, siluc);
  smallmm_k<<<dim3(24, 32), 256, 0, stream>>>(siluc, ada_w, ada_b, gss, 6144);
  smallmm_k<<<dim3(8, 32), 256, 0, stream>>>(siluc, head_ada_w, head_ada_b, ss, 2048);
  eprep_k<<<dim3(400, 2), 256, 0, stream>>>(x_blcv, poc_ctx, A0, A1);
  tconv_k<<<dim3(16, 1), 256, 0, stream>>>(word_w, wwt, 64, 1024);
  egemm_k<<<dim3(100, 16), 256, 0, stream>>>(A0, A1, wwt, word_b, lvl_tab, pos_1lc,
                                             cond, pos_start, x, poc);

  for (int d = 0; d < 8; d++) {
    const float* ag = ada_gss + (size_t)d * 6144;
    tconv5_k<<<2048, 256, 0, stream>>>(
        q_w + (size_t)d * 1048576, kv_w + (size_t)d * 2097152,
        proj_w + (size_t)d * 1048576, fc1_w + (size_t)d * 4194304,
        qwt, kvwt, pjwt, f1wt);
    tconv_k<<<dim3(16, 64), 256, 0, stream>>>(fc2_w + (size_t)d * 4194304, f2wt, 4096, 1024);

    ln2_k<<<3200, 256, 0, stream>>>(x, xn, ag + 2 * 1024, gss + 2 * 1024, 6144,
                                    ag + 4 * 1024, gss + 4 * 1024, 6144);
    qkv_k<<<dim3(100, 24), 256, 0, stream>>>(
        xn, poc, qwt, kvwt, q_b + d * 1024, kv_b + d * 2048, qbf, kbuf, vtb);
    attn3_k<<<dim3(512, 4), 512, 0, stream>>>(qbf, kbuf, vtb, ob);
    gemm2_k<EP_RESID><<<dim3(100, 8), 256, 0, stream>>>(
        ob, pjwt, proj_b + d * 1024, nullptr, x, ag + 0, gss + 0, nullptr, 1024, 1024);
    ln2_k<<<3200, 256, 0, stream>>>(x, xn, ag + 3 * 1024, gss + 3 * 1024, 6144,
                                    ag + 5 * 1024, gss + 5 * 1024, 6144);
    gemm4_k<EP_GELU><<<dim3(50, 32), 512, 0, stream>>>(
        xn, f1wt, fc1_b + d * 4096, hdn, nullptr, nullptr, nullptr, 4096, 1024);
    gemm4_k<EP_RESID><<<dim3(50, 8), 512, 0, stream>>>(
        hdn, f2wt, fc2_b + d * 1024, nullptr, x, ag + 1024, gss + 1024, 1024, 4096);
  }
  ln2_k<<<3200, 256, 0, stream>>>(x, xn, nullptr, ss, 2048, nullptr, ss + 1024, 2048);
  tconv_k<<<dim3(64, 16), 256, 0, stream>>>(head_w, wt, 1024, 4096);
  gemm4_k<EP_F32><<<dim3(50, 32), 512, 0, stream>>>(
      xn, wt, head_b, d_out, nullptr, nullptr, nullptr, 4096, 1024);
}

// Round 14
// 5938.921 us; speedup vs baseline: 1.0381x; 1.0381x over previous
//
#include <hip/hip_runtime.h>
#include <hip/hip_bf16.h>
#include <math.h>

#define DEV __device__ __forceinline__

typedef __attribute__((ext_vector_type(4))) float f32x4;
typedef __attribute__((ext_vector_type(8))) short bf16x8;
typedef __attribute__((ext_vector_type(4))) short s16x4;

static constexpr int Bz = 32, Lz = 400, Cz = 1024, MLPz = 4096;
static constexpr int BL = Bz * Lz;  // 12800

DEV float bf2f(unsigned short u) {
  union { unsigned int i; float f; } v; v.i = ((unsigned int)u) << 16; return v.f;
}
DEV unsigned short f2bf(float f) {
  union { float f; unsigned int i; } v; v.f = f;
  unsigned int r = v.i + 0x7FFFu + ((v.i >> 16) & 1u);
  return (unsigned short)(r >> 16);
}

DEV int level_of(int l) {
  const int cum[13] = {1,3,6,10,16,25,38,57,84,124,184,272,400};
  int lv = 12;
  #pragma unroll
  for (int i = 12; i >= 0; i--) if (l < cum[i]) lv = i;
  return lv;
}
DEV int row_kmax(int l) {
  const int cum[13] = {1,3,6,10,16,25,38,57,84,124,184,272,400};
  int km = 400;
  #pragma unroll
  for (int i = 12; i >= 0; i--) if (l < cum[i]) km = cum[i];
  return km;
}

DEV void stage16(const unsigned short* g, unsigned short* l) {
#if __has_builtin(__builtin_amdgcn_global_load_lds)
  __builtin_amdgcn_global_load_lds((const __attribute__((address_space(1))) void*)g,
                                   (__attribute__((address_space(3))) void*)l, 16, 0, 0);
#else
  *(bf16x8*)l = *(const bf16x8*)g;
#endif
}

// ------------------------------------------------------- weight transpose/convert
__global__ __launch_bounds__(256)
void tconv_k(const float* __restrict__ in, unsigned short* __restrict__ out, int K, int N)
{
  __shared__ float t[64][65];
  const int n0 = blockIdx.x * 64, k0 = blockIdx.y * 64;
  #pragma unroll
  for (int i = 0; i < 16; i++) {
    int idx = i * 256 + threadIdx.x;
    int r = idx >> 6, c = idx & 63;
    t[r][c] = in[(size_t)(k0 + r) * N + n0 + c];
  }
  __syncthreads();
  #pragma unroll
  for (int i = 0; i < 16; i++) {
    int idx = i * 256 + threadIdx.x;
    int rn = idx >> 6, ck = idx & 63;
    out[(size_t)(n0 + rn) * K + k0 + ck] = f2bf(t[ck][rn]);
  }
}

// exact-grid merged per-depth transpose (q, kv, proj, fc1; all K=1024).
__global__ __launch_bounds__(256)
void tconv5_k(const float* __restrict__ qw, const float* __restrict__ kvw,
              const float* __restrict__ pjw, const float* __restrict__ f1w,
              unsigned short* __restrict__ qwt, unsigned short* __restrict__ kvwt,
              unsigned short* __restrict__ pjwt, unsigned short* __restrict__ f1wt)
{
  const int bid = blockIdx.x;
  const float* in; unsigned short* out; int N, n0, k0;
  if (bid < 256)       { in = qw;  out = qwt;  N = 1024; int t = bid;        n0 = (t & 15) * 64; k0 = (t >> 4) * 64; }
  else if (bid < 768)  { in = kvw; out = kvwt; N = 2048; int t = bid - 256;  n0 = (t & 31) * 64; k0 = (t >> 5) * 64; }
  else if (bid < 1024) { in = pjw; out = pjwt; N = 1024; int t = bid - 768;  n0 = (t & 15) * 64; k0 = (t >> 4) * 64; }
  else                 { in = f1w; out = f1wt; N = 4096; int t = bid - 1024; n0 = (t & 63) * 64; k0 = (t >> 6) * 64; }
  __shared__ float tt[64][65];
  #pragma unroll
  for (int i = 0; i < 16; i++) {
    int idx = i * 256 + threadIdx.x;
    int r = idx >> 6, c = idx & 63;
    tt[r][c] = in[(size_t)(k0 + r) * N + n0 + c];
  }
  __syncthreads();
  #pragma unroll
  for (int i = 0; i < 16; i++) {
    int idx = i * 256 + threadIdx.x;
    int rn = idx >> 6, ck = idx & 63;
    out[(size_t)(n0 + rn) * 1024 + k0 + ck] = f2bf(tt[ck][rn]);
  }
}

// ---------------------------------------------------------------- GEMM (m97-style, proven round-3 form)
// RULES (r4/r5/r6/r13 ledger): 128x128 tile, 4 waves, (256,2) ONLY.
//  - (512,4) NaN; (256,4) untestable-confounded; fatter tiles (256x128 @8w)
//    regress (barrier width + blocks/CU drop); XCD swizzle regresses (+80% FETCH);
//    8-phase regresses at 1 block/CU. This structure is the measured optimum here.
enum { EP_BF16 = 0, EP_GELU = 1, EP_RESID = 2, EP_F32 = 3, EP_KV = 4 };

template<int MODE>
__global__ __launch_bounds__(256, 2)
void gemm2_k(const unsigned short* __restrict__ A, const unsigned short* __restrict__ Bt,
             const float* __restrict__ bias, void* __restrict__ out,
             float* __restrict__ xres, const float* __restrict__ gsh,
             const float* __restrict__ gpb, unsigned short* __restrict__ vtb,
             int N, int K)
{
  __shared__ unsigned short As[128 * 64];
  __shared__ unsigned short Bs[128 * 64];
  const int tid = threadIdx.x;
  const int lane = tid & 63, wv = tid >> 6;
  const int row0 = blockIdx.x * 128, col0 = blockIdx.y * 128;
  const int wm = (wv >> 1) * 64, wn = (wv & 1) * 64;

  f32x4 acc[4][4] = {};

  for (int k0 = 0; k0 < K; k0 += 64) {
    #pragma unroll
    for (int i = 0; i < 4; i++) {
      int ch = i * 256 + tid;
      int r = ch >> 3;
      int c8 = (ch & 7) ^ (r & 7);
      stage16(A + (size_t)(row0 + r) * K + k0 + c8 * 8, As + ch * 8);
    }
    #pragma unroll
    for (int i = 0; i < 4; i++) {
      int ch = i * 256 + tid;
      int r = ch >> 3;
      int c8 = (ch & 7) ^ (r & 7);
      stage16(Bt + (size_t)(col0 + r) * K + k0 + c8 * 8, Bs + ch * 8);
    }
    __syncthreads();
    #pragma unroll
    for (int kk = 0; kk < 2; kk++) {
      bf16x8 af[4], bfr[4];
      const int bcol = kk * 64 + (lane >> 4) * 16;
      #pragma unroll
      for (int m = 0; m < 4; m++) {
        int r = wm + m * 16 + (lane & 15);
        af[m] = *(const bf16x8*)((char*)As + r * 128 + (bcol ^ ((r & 7) << 4)));
      }
      #pragma unroll
      for (int n = 0; n < 4; n++) {
        int r = wn + n * 16 + (lane & 15);
        bfr[n] = *(const bf16x8*)((char*)Bs + r * 128 + (bcol ^ ((r & 7) << 4)));
      }
      #pragma unroll
      for (int m = 0; m < 4; m++)
        #pragma unroll
        for (int n = 0; n < 4; n++)
          acc[m][n] = __builtin_amdgcn_mfma_f32_16x16x32_bf16(af[m], bfr[n], acc[m][n], 0, 0, 0);
    }
    __syncthreads();
  }

  const int rbase = row0 + wm + ((lane >> 4) << 2);
  const int cbase = col0 + wn + (lane & 15);
  #pragma unroll
  for (int n = 0; n < 4; n++) {
    int gcol = cbase + n * 16;
    float bv = bias[gcol];
    #pragma unroll
    for (int m = 0; m < 4; m++) {
      #pragma unroll
      for (int r = 0; r < 4; r++) {
        int grow = rbase + m * 16 + r;
        float v = acc[m][n][r] + bv;
        if constexpr (MODE == EP_BF16) {
          ((unsigned short*)out)[(size_t)grow * N + gcol] = f2bf(v);
        } else if constexpr (MODE == EP_GELU) {
          float g = 0.5f * v * (1.f + erff(v * 0.70710678118654752f));
          ((unsigned short*)out)[(size_t)grow * N + gcol] = f2bf(g);
        } else if constexpr (MODE == EP_RESID) {
          int b = grow / Lz;
          float g = gsh[gcol] + gpb[(size_t)b * 6144 + gcol];
          xres[(size_t)grow * Cz + gcol] += g * v;
        } else if constexpr (MODE == EP_KV) {
          if (gcol < 1024) {
            ((unsigned short*)out)[(size_t)grow * 1024 + gcol] = f2bf(v);  // K row-major
          } else {
            int b = grow / Lz, l = grow - b * Lz;
            int h = (gcol >> 6) & 15, d = gcol & 63;
            vtb[(((size_t)b * 16 + h) * 64 + d) * Lz + l] = f2bf(v);      // V transposed
          }
        } else {
          ((float*)out)[(size_t)grow * N + gcol] = v;
        }
      }
    }
  }
}

// ---------------------------------------------------------------- merged q + kv GEMM (K=1024)
__global__ __launch_bounds__(256, 2)
void qkv_k(const unsigned short* __restrict__ xn, const unsigned short* __restrict__ poc,
           const unsigned short* __restrict__ qwt, const unsigned short* __restrict__ kvwt,
           const float* __restrict__ q_bias, const float* __restrict__ kv_bias,
           unsigned short* __restrict__ qbf, unsigned short* __restrict__ kbuf,
           unsigned short* __restrict__ vtb)
{
  __shared__ unsigned short As[128 * 64];
  __shared__ unsigned short Bs[128 * 64];
  const int tid = threadIdx.x;
  const int lane = tid & 63, wv = tid >> 6;
  const bool isq = blockIdx.y < 8;
  const unsigned short* A  = isq ? xn : poc;
  const unsigned short* Bt = isq ? qwt : kvwt;
  const float* bias        = isq ? q_bias : kv_bias;
  const int K = 1024;
  const int row0 = blockIdx.x * 128;
  const int col0 = (isq ? blockIdx.y : (blockIdx.y - 8)) * 128;
  const int wm = (wv >> 1) * 64, wn = (wv & 1) * 64;

  f32x4 acc[4][4] = {};

  for (int k0 = 0; k0 < K; k0 += 64) {
    #pragma unroll
    for (int i = 0; i < 4; i++) {
      int ch = i * 256 + tid;
      int r = ch >> 3;
      int c8 = (ch & 7) ^ (r & 7);
      stage16(A + (size_t)(row0 + r) * K + k0 + c8 * 8, As + ch * 8);
    }
    #pragma unroll
    for (int i = 0; i < 4; i++) {
      int ch = i * 256 + tid;
      int r = ch >> 3;
      int c8 = (ch & 7) ^ (r & 7);
      stage16(Bt + (size_t)(col0 + r) * K + k0 + c8 * 8, Bs + ch * 8);
    }
    __syncthreads();
    #pragma unroll
    for (int kk = 0; kk < 2; kk++) {
      bf16x8 af[4], bfr[4];
      const int bcol = kk * 64 + (lane >> 4) * 16;
      #pragma unroll
      for (int m = 0; m < 4; m++) {
        int r = wm + m * 16 + (lane & 15);
        af[m] = *(const bf16x8*)((char*)As + r * 128 + (bcol ^ ((r & 7) << 4)));
      }
      #pragma unroll
      for (int n = 0; n < 4; n++) {
        int r = wn + n * 16 + (lane & 15);
        bfr[n] = *(const bf16x8*)((char*)Bs + r * 128 + (bcol ^ ((r & 7) << 4)));
      }
      #pragma unroll
      for (int m = 0; m < 4; m++)
        #pragma unroll
        for (int n = 0; n < 4; n++)
          acc[m][n] = __builtin_amdgcn_mfma_f32_16x16x32_bf16(af[m], bfr[n], acc[m][n], 0, 0, 0);
    }
    __syncthreads();
  }

  const int rbase = row0 + wm + ((lane >> 4) << 2);
  const int cbase = col0 + wn + (lane & 15);
  #pragma unroll
  for (int n = 0; n < 4; n++) {
    int gcol = cbase + n * 16;
    float bv = bias[gcol];
    #pragma unroll
    for (int m = 0; m < 4; m++) {
      #pragma unroll
      for (int r = 0; r < 4; r++) {
        int grow = rbase + m * 16 + r;
        float v = acc[m][n][r] + bv;
        if (isq) {
          qbf[(size_t)grow * 1024 + gcol] = f2bf(v);
        } else if (gcol < 1024) {
          kbuf[(size_t)grow * 1024 + gcol] = f2bf(v);
        } else {
          int b = grow / Lz, l = grow - b * Lz;
          int h = (gcol >> 6) & 15, d = gcol & 63;
          vtb[(((size_t)b * 16 + h) * 64 + d) * Lz + l] = f2bf(v);
        }
      }
    }
  }
}

// ---------------------------------------------------------------- embed prep: f32 -> bf16 A matrices
__global__ __launch_bounds__(256)
void eprep_k(const float* __restrict__ src0, const float* __restrict__ src1,
             unsigned short* __restrict__ A0, unsigned short* __restrict__ A1)
{
  const int chunk = blockIdx.x * 256 + threadIdx.x;
  const int row = chunk >> 3, k8 = (chunk & 7) * 8;
  bf16x8 o;
  if (blockIdx.y == 0) {
    const int b = row / Lz, l = row - b * Lz;
    if (l == 0) {
      #pragma unroll
      for (int i = 0; i < 8; i++) o[i] = 0;
    } else {
      const float* s = src0 + ((size_t)b * (Lz - 1) + (l - 1)) * 64 + k8;
      #pragma unroll
      for (int i = 0; i < 8; i++) o[i] = (short)f2bf(s[i]);
    }
    *(bf16x8*)(A0 + (size_t)row * 64 + k8) = o;
  } else {
    const float* s = src1 + (size_t)row * 64 + k8;
    #pragma unroll
    for (int i = 0; i < 8; i++) o[i] = (short)f2bf(s[i]);
    *(bf16x8*)(A1 + (size_t)row * 64 + k8) = o;
  }
}

// ---------------------------------------------------------------- embed GEMM: K=64, single K-step
__global__ __launch_bounds__(256, 2)
void egemm_k(const unsigned short* __restrict__ A0, const unsigned short* __restrict__ A1,
             const unsigned short* __restrict__ wwt, const float* __restrict__ wb,
             const float* __restrict__ ltab, const float* __restrict__ pos1,
             const float* __restrict__ cond, const float* __restrict__ pos_start,
             float* __restrict__ xout, unsigned short* __restrict__ pocout)
{
  __shared__ unsigned short As[128 * 64];
  __shared__ unsigned short Bs[128 * 64];
  const int tid = threadIdx.x;
  const int lane = tid & 63, wv = tid >> 6;
  const int mode = blockIdx.y >> 3;
  const int col0 = (blockIdx.y & 7) * 128;
  const int row0 = blockIdx.x * 128;
  const unsigned short* A = mode ? A1 : A0;
  const int wm = (wv >> 1) * 64, wn = (wv & 1) * 64;

  f32x4 acc[4][4] = {};

  #pragma unroll
  for (int i = 0; i < 4; i++) {
    int ch = i * 256 + tid;
    int r = ch >> 3;
    int c8 = (ch & 7) ^ (r & 7);
    stage16(A + (size_t)(row0 + r) * 64 + c8 * 8, As + ch * 8);
  }
  #pragma unroll
  for (int i = 0; i < 4; i++) {
    int ch = i * 256 + tid;
    int r = ch >> 3;
    int c8 = (ch & 7) ^ (r & 7);
    stage16(wwt + (size_t)(col0 + r) * 64 + c8 * 8, Bs + ch * 8);
  }
  __syncthreads();
  #pragma unroll
  for (int kk = 0; kk < 2; kk++) {
    bf16x8 af[4], bfr[4];
    const int bcol = kk * 64 + (lane >> 4) * 16;
    #pragma unroll
    for (int m = 0; m < 4; m++) {
      int r = wm + m * 16 + (lane & 15);
      af[m] = *(const bf16x8*)((char*)As + r * 128 + (bcol ^ ((r & 7) << 4)));
    }
    #pragma unroll
    for (int n = 0; n < 4; n++) {
      int r = wn + n * 16 + (lane & 15);
      bfr[n] = *(const bf16x8*)((char*)Bs + r * 128 + (bcol ^ ((r & 7) << 4)));
    }
    #pragma unroll
    for (int m = 0; m < 4; m++)
      #pragma unroll
      for (int n = 0; n < 4; n++)
        acc[m][n] = __builtin_amdgcn_mfma_f32_16x16x32_bf16(af[m], bfr[n], acc[m][n], 0, 0, 0);
  }

  const int rbase = row0 + wm + ((lane >> 4) << 2);
  const int cbase = col0 + wn + (lane & 15);
  #pragma unroll
  for (int n = 0; n < 4; n++) {
    int gcol = cbase + n * 16;
    float bv = wb[gcol];
    #pragma unroll
    for (int m = 0; m < 4; m++) {
      #pragma unroll
      for (int r = 0; r < 4; r++) {
        int grow = rbase + m * 16 + r;
        int b = grow / Lz, l = grow - b * Lz;
        float base = ltab[(size_t)level_of(l) * Cz + gcol] + pos1[(size_t)l * Cz + gcol];
        float v = acc[m][n][r] + bv + base;
        if (mode == 0) {
          if (l == 0) v = cond[(size_t)b * Cz + gcol] + pos_start[gcol] + ltab[gcol] + pos1[gcol];
          xout[(size_t)grow * Cz + gcol] = v;
        } else {
          pocout[(size_t)grow * Cz + gcol] = f2bf(v);
        }
      }
    }
  }
}

// ---------------------------------------------------------------- LayerNorm v2: wave-per-row, no barriers
__global__ __launch_bounds__(256)
void ln2_k(const float* __restrict__ x, unsigned short* __restrict__ out,
           const float* __restrict__ ssh, const float* __restrict__ spb, int sstride,
           const float* __restrict__ hsh, const float* __restrict__ hpb, int hstride)
{
  const int wv = threadIdx.x >> 6, lane = threadIdx.x & 63;
  const int row = blockIdx.x * 4 + wv;
  const int b = row / Lz;
  const float* xr = x + (size_t)row * Cz;
  f32x4 v[4];
  float s1 = 0.f;
  #pragma unroll
  for (int j = 0; j < 4; j++) {
    v[j] = *(const f32x4*)(xr + j * 256 + lane * 4);
    s1 += v[j][0] + v[j][1] + v[j][2] + v[j][3];
  }
  #pragma unroll
  for (int o = 32; o > 0; o >>= 1) s1 += __shfl_xor(s1, o, 64);
  float mean = s1 * (1.f / 1024.f);
  float s2 = 0.f;
  #pragma unroll
  for (int j = 0; j < 4; j++)
    #pragma unroll
    for (int i = 0; i < 4; i++) { float d = v[j][i] - mean; s2 += d * d; }
  #pragma unroll
  for (int o = 32; o > 0; o >>= 1) s2 += __shfl_xor(s2, o, 64);
  float rstd = rsqrtf(s2 * (1.f / 1024.f) + 1e-6f);
  #pragma unroll
  for (int j = 0; j < 4; j++) {
    s16x4 o4;
    #pragma unroll
    for (int i = 0; i < 4; i++) {
      int c = j * 256 + lane * 4 + i;
      float sc = (ssh ? ssh[c] : 0.f) + spb[(size_t)b * sstride + c];
      float sh = (hsh ? hsh[c] : 0.f) + hpb[(size_t)b * hstride + c];
      o4[i] = (short)f2bf((v[j][i] - mean) * rstd * (1.f + sc) + sh);
    }
    *(s16x4*)(&out[(size_t)row * Cz + j * 256 + lane * 4]) = o4;
  }
}

// ---------------------------------------------------------------- attention v6 (MFMA PV)
__global__ __launch_bounds__(512)
void attn3_k(const unsigned short* __restrict__ qb,
             const unsigned short* __restrict__ kbuf,
             const unsigned short* __restrict__ vtb,
             unsigned short* __restrict__ ob)
{
  __shared__ unsigned short Ks[400 * 64];     // swizzled rows, 128 B/row
  __shared__ unsigned short Vt[64 * 408];     // V^T, pitch 816 B
  __shared__ unsigned short Pl[8][512];       // per-wave P buffer (16q x 32k bf16)
  const int bh = blockIdx.x, b = bh >> 4, h = bh & 15;
  const int qc = blockIdx.y;
  const int tid = threadIdx.x;
  const int q0 = qc * 128;
  const int nch = (row_kmax(min(q0 + 127, Lz - 1)) + 15) >> 4;

  const size_t kbase = (size_t)b * Lz * 1024 + h * 64;
  for (int i = tid; i < nch * 128; i += 512) {
    int l = i >> 3, d8 = i & 7;
    bf16x8 kr = *(const bf16x8*)&kbuf[kbase + (size_t)l * 1024 + d8 * 8];
    *(bf16x8*)((char*)Ks + l * 128 + ((d8 * 16) ^ ((l & 7) << 4))) = kr;
  }
  const size_t vbase = ((size_t)b * 16 + h) * 64 * Lz;
  const int vch = nch * 2;                     // staged 16B chunks per d-row
  for (int i = tid; i < 3200; i += 512) {      // 64 d-rows x 50 chunk slots
    int d = i / 50, c8 = i - d * 50;           // constant divisor -> magic mul
    if (c8 < vch)
      *(bf16x8*)((char*)Vt + d * 816 + c8 * 16) = *(const bf16x8*)&vtb[vbase + (size_t)d * Lz + c8 * 8];
  }
  __syncthreads();

  const int wv = tid >> 6, lane = tid & 63, g = lane >> 4, q = lane & 15;
  const int qw0 = q0 + wv * 16;
  if (qw0 >= Lz) return;
  const int qrow = qw0 + q;
  const int my_kmax = row_kmax(qrow);
  const int nsch = (row_kmax(qw0 + 15) + 31) >> 5;
  const int vclamp = nch * 16 - 8;             // max legal 8-elem fragment start

  const unsigned short* qp = qb + (size_t)(b * Lz + qrow) * Cz + h * 64;
  bf16x8 qf0 = *(const bf16x8*)(qp + g * 8);
  bf16x8 qf1 = *(const bf16x8*)(qp + 32 + g * 8);
  unsigned short* myP = &Pl[wv][0];

  float m = -30000.f, lsum = 0.f;
  f32x4 acc[4] = {};

  for (int sc = 0; sc < nsch; ++sc) {
    f32x4 st0 = {0.f,0.f,0.f,0.f}, st1 = {0.f,0.f,0.f,0.f};
    {
      int kr = sc * 32 + q;
      const char* kb = (const char*)Ks + kr * 128;
      int sw = (kr & 7) << 4;
      bf16x8 k0 = *(const bf16x8*)(kb + ((g * 16) ^ sw));
      bf16x8 k1 = *(const bf16x8*)(kb + ((64 + g * 16) ^ sw));
      st0 = __builtin_amdgcn_mfma_f32_16x16x32_bf16(k0, qf0, st0, 0, 0, 0);
      st0 = __builtin_amdgcn_mfma_f32_16x16x32_bf16(k1, qf1, st0, 0, 0, 0);
    }
    {
      int kr = sc * 32 + 16 + q;
      const char* kb = (const char*)Ks + kr * 128;
      int sw = (kr & 7) << 4;
      bf16x8 k0 = *(const bf16x8*)(kb + ((g * 16) ^ sw));
      bf16x8 k1 = *(const bf16x8*)(kb + ((64 + g * 16) ^ sw));
      st1 = __builtin_amdgcn_mfma_f32_16x16x32_bf16(k0, qf0, st1, 0, 0, 0);
      st1 = __builtin_amdgcn_mfma_f32_16x16x32_bf16(k1, qf1, st1, 0, 0, 0);
    }

    float s8[8]; float cmax = -30000.f;
    #pragma unroll
    for (int r = 0; r < 4; r++) {
      int k0g = sc * 32 + 4 * g + r;
      int k1g = k0g + 16;
      s8[r]     = (k0g < my_kmax) ? st0[r] * 0.125f : -30000.f;
      s8[4 + r] = (k1g < my_kmax) ? st1[r] * 0.125f : -30000.f;
      cmax = fmaxf(cmax, fmaxf(s8[r], s8[4 + r]));
    }
    cmax = fmaxf(cmax, __shfl_xor(cmax, 16, 64));
    cmax = fmaxf(cmax, __shfl_xor(cmax, 32, 64));

    if (!__all(cmax <= m + 8.f)) {
      float mnew = fmaxf(m, cmax);
      float f = __expf(m - mnew);
      lsum *= f;
      #pragma unroll
      for (int blk = 0; blk < 4; blk++)
        #pragma unroll
        for (int j = 0; j < 4; j++) acc[blk][j] *= f;
      m = mnew;
    }

    float p[8], ps = 0.f;
    #pragma unroll
    for (int r = 0; r < 8; r++) { p[r] = __expf(s8[r] - m); ps += p[r]; }
    ps += __shfl_xor(ps, 16, 64);
    ps += __shfl_xor(ps, 32, 64);
    lsum += ps;

    #pragma unroll
    for (int cp = 0; cp < 2; cp++) {
      #pragma unroll
      for (int j = 0; j < 2; j++) {
        unsigned int pk;
        asm("v_cvt_pk_bf16_f32 %0, %1, %2" : "=v"(pk)
            : "v"(p[4 * cp + 2 * j]), "v"(p[4 * cp + 2 * j + 1]));
        int w = 8 * cp + 2 * g + j;
        *(unsigned int*)((char*)myP + q * 64 + 4 * (w ^ q)) = pk;
      }
    }

    unsigned int pw[4];
    #pragma unroll
    for (int i = 0; i < 4; i++)
      pw[i] = *(const unsigned int*)((const char*)myP + q * 64 + 4 * ((4 * g + i) ^ q));
    bf16x8 pfrag;
    #pragma unroll
    for (int i = 0; i < 4; i++) {
      pfrag[2 * i]     = (short)(pw[i] & 0xFFFF);
      pfrag[2 * i + 1] = (short)(pw[i] >> 16);
    }

    const int koff = min(sc * 32 + 8 * g, vclamp);   // clamp into staged region
    #pragma unroll
    for (int blk = 0; blk < 4; blk++) {
      bf16x8 vf = *(const bf16x8*)((const char*)Vt + (16 * blk + q) * 816 + koff * 2);
      acc[blk] = __builtin_amdgcn_mfma_f32_16x16x32_bf16(vf, pfrag, acc[blk], 0, 0, 0);
    }
  }

  float inv = 1.f / lsum;
  unsigned short* op = ob + (size_t)(b * Lz + qrow) * Cz + h * 64;
  #pragma unroll
  for (int blk = 0; blk < 4; blk++)
    #pragma unroll
    for (int r = 0; r < 4; r++)
      op[16 * blk + 4 * g + r] = f2bf(acc[blk][r] * inv);
}

// ---------------------------------------------------------------- preamble
__global__ __launch_bounds__(256)
void cond_k(const float* __restrict__ pc, const float* __restrict__ pw,
            const float* __restrict__ pb, float* __restrict__ cond,
            float* __restrict__ silu)
{
  const int b = blockIdx.y;
  const int n = blockIdx.x * 256 + threadIdx.x;
  __shared__ float a[256];
  a[threadIdx.x] = pc[b * 256 + threadIdx.x];
  __syncthreads();
  float s = pb[n];
  for (int k = 0; k < 256; k++) s += a[k] * pw[(size_t)k * Cz + n];
  cond[(size_t)b * Cz + n] = s;
  silu[(size_t)b * Cz + n] = s / (1.f + __expf(-s));
}

__global__ __launch_bounds__(256)
void smallmm_k(const float* __restrict__ A, const float* __restrict__ W,
               const float* __restrict__ bias, float* __restrict__ out, int N)
{
  const int b = blockIdx.y;
  const int n = blockIdx.x * 256 + threadIdx.x;
  __shared__ float a[1024];
  for (int i = threadIdx.x; i < 1024; i += 256) a[i] = A[(size_t)b * 1024 + i];
  __syncthreads();
  float s = bias[n];
  for (int k = 0; k < 1024; k++) s += a[k] * W[(size_t)k * N + n];
  out[(size_t)b * N + n] = s;
}

// ---------------------------------------------------------------- launch
extern "C" void kernel_launch(void* const* d_in, const int* in_sizes, int n_in,
                              void* d_out, int out_size, void* d_ws, size_t ws_size,
                              hipStream_t stream)
{
  (void)in_sizes; (void)n_in; (void)out_size; (void)ws_size;
  const float* x_blcv   = (const float*)d_in[0];
  const float* poc_ctx  = (const float*)d_in[1];
  const float* poc_cond = (const float*)d_in[2];
  const float* word_w   = (const float*)d_in[3];
  const float* word_b   = (const float*)d_in[4];
  const float* poc_w    = (const float*)d_in[5];
  const float* poc_b    = (const float*)d_in[6];
  const float* pos_start= (const float*)d_in[7];
  const float* pos_1lc  = (const float*)d_in[8];
  const float* lvl_tab  = (const float*)d_in[9];
  const float* ada_w    = (const float*)d_in[10];
  const float* ada_b    = (const float*)d_in[11];
  const float* ada_gss  = (const float*)d_in[12];
  const float* q_w      = (const float*)d_in[13];
  const float* q_b      = (const float*)d_in[14];
  const float* kv_w     = (const float*)d_in[15];
  const float* kv_b     = (const float*)d_in[16];
  const float* proj_w   = (const float*)d_in[17];
  const float* proj_b   = (const float*)d_in[18];
  const float* fc1_w    = (const float*)d_in[19];
  const float* fc1_b    = (const float*)d_in[20];
  const float* fc2_w    = (const float*)d_in[21];
  const float* fc2_b    = (const float*)d_in[22];
  const float* head_ada_w = (const float*)d_in[23];
  const float* head_ada_b = (const float*)d_in[24];
  const float* head_w   = (const float*)d_in[25];
  const float* head_b   = (const float*)d_in[26];

  char* p = (char*)d_ws;
  auto carve = [&](size_t bytes) { void* r = (void*)p; p += (bytes + 255) & ~(size_t)255; return r; };
  float* x            = (float*)carve((size_t)BL * Cz * 4);
  unsigned short* xn  = (unsigned short*)carve((size_t)BL * Cz * 2);
  unsigned short* poc = (unsigned short*)carve((size_t)BL * Cz * 2);
  unsigned short* qbf = (unsigned short*)carve((size_t)BL * Cz * 2);
  unsigned short* kbuf= (unsigned short*)carve((size_t)BL * Cz * 2);
  unsigned short* vtb = (unsigned short*)carve((size_t)BL * Cz * 2);
  unsigned short* ob  = (unsigned short*)carve((size_t)BL * Cz * 2);
  unsigned short* hdn = (unsigned short*)carve((size_t)BL * MLPz * 2);
  unsigned short* wt  = (unsigned short*)carve((size_t)12582912 * 2);
  unsigned short* A0  = (unsigned short*)carve((size_t)BL * 64 * 2);
  unsigned short* A1  = (unsigned short*)carve((size_t)BL * 64 * 2);
  unsigned short* wwt = (unsigned short*)carve((size_t)1024 * 64 * 2);
  float* cond  = (float*)carve(32 * 1024 * 4);
  float* siluc = (float*)carve(32 * 1024 * 4);
  float* gss   = (float*)carve(32 * 6144 * 4);
  float* ss    = (float*)carve(32 * 2048 * 4);

  unsigned short* qwt  = wt;
  unsigned short* kvwt = wt + 1048576;
  unsigned short* pjwt = wt + 3145728;
  unsigned short* f1wt = wt + 4194304;
  unsigned short* f2wt = wt + 8388608;

  cond_k<<<dim3(4, 32), 256, 0, stream>>>(poc_cond, poc_w, poc_b, cond, siluc);
  smallmm_k<<<dim3(24, 32), 256, 0, stream>>>(siluc, ada_w, ada_b, gss, 6144);
  smallmm_k<<<dim3(8, 32), 256, 0, stream>>>(siluc, head_ada_w, head_ada_b, ss, 2048);
  eprep_k<<<dim3(400, 2), 256, 0, stream>>>(x_blcv, poc_ctx, A0, A1);
  tconv_k<<<dim3(16, 1), 256, 0, stream>>>(word_w, wwt, 64, 1024);
  egemm_k<<<dim3(100, 16), 256, 0, stream>>>(A0, A1, wwt, word_b, lvl_tab, pos_1lc,
                                             cond, pos_start, x, poc);

  for (int d = 0; d < 8; d++) {
    const float* ag = ada_gss + (size_t)d * 6144;
    tconv5_k<<<2048, 256, 0, stream>>>(
        q_w + (size_t)d * 1048576, kv_w + (size_t)d * 2097152,
        proj_w + (size_t)d * 1048576, fc1_w + (size_t)d * 4194304,
        qwt, kvwt, pjwt, f1wt);
    tconv_k<<<dim3(16, 64), 256, 0, stream>>>(fc2_w + (size_t)d * 4194304, f2wt, 4096, 1024);

    ln2_k<<<3200, 256, 0, stream>>>(x, xn, ag + 2 * 1024, gss + 2 * 1024, 6144,
                                    ag + 4 * 1024, gss + 4 * 1024, 6144);
    qkv_k<<<dim3(100, 24), 256, 0, stream>>>(
        xn, poc, qwt, kvwt, q_b + d * 1024, kv_b + d * 2048, qbf, kbuf, vtb);
    attn3_k<<<dim3(512, 4), 512, 0, stream>>>(qbf, kbuf, vtb, ob);
    gemm2_k<EP_RESID><<<dim3(100, 8), 256, 0, stream>>>(
        ob, pjwt, proj_b + d * 1024, nullptr, x, ag + 0, gss + 0, nullptr, 1024, 1024);
    ln2_k<<<3200, 256, 0, stream>>>(x, xn, ag + 3 * 1024, gss + 3 * 1024, 6144,
                                    ag + 5 * 1024, gss + 5 * 1024, 6144);
    gemm2_k<EP_GELU><<<dim3(100, 32), 256, 0, stream>>>(
        xn, f1wt, fc1_b + d * 4096, hdn, nullptr, nullptr, nullptr, nullptr, 4096, 1024);
    gemm2_k<EP_RESID><<<dim3(100, 8), 256, 0, stream>>>(
        hdn, f2wt, fc2_b + d * 1024, nullptr, x, ag + 1024, gss + 1024, nullptr, 1024, 4096);
  }
  ln2_k<<<3200, 256, 0, stream>>>(x, xn, nullptr, ss, 2048, nullptr, ss + 1024, 2048);
  tconv_k<<<dim3(64, 16), 256, 0, stream>>>(head_w, wt, 1024, 4096);
  gemm2_k<EP_F32><<<dim3(100, 32), 256, 0, stream>>>(
      xn, wt, head_b, d_out, nullptr, nullptr, nullptr, nullptr, 4096, 1024);
}